// Round 1
// baseline (130.410 us; speedup 1.0000x reference)
//
#include <hip/hip_runtime.h>
#include <hip/hip_bf16.h>

// CausalGraphDiscovery on MI355X. f32 buffers holding bf16-rounded values.
// Round 7: SINGLE dispatch, zero inter-block dependencies.
//   Previous structure: k_main (graph chain w/ flag-spin + pair MLP) then
//   k_mech serialized behind the full k_main drain. Both kernels measured
//   <40us each (hidden under the harness's 40us 256MiB ws-poison fills in
//   top-5), so the remaining cost is structural: 2 launches + serialization
//   + flag-spin. Round-5 lesson: fusion via MASS SPIN-WAIT collapses
//   (memory congestion). This round fuses via REDUNDANT RECOMPUTE instead:
//   the graph chain is ~0.7 MFLOP + ~1MB of L2-resident reads, so each mech
//   block recomputes it locally (bit-identical across blocks -> consistent
//   pm), eliminating all producer/consumer coupling.
//
// Grid: 496 blocks x 256 threads, all co-resident (2 blocks/CU, 44KB LDS).
//   bid   0..255: mech block (v = bid>>4, chunk of 512 samples = bid&15)
//                 phase A: graph chain (av -> cov -> corr -> MLP -> adj -> pm/hp)
//                 phase B: bf16-MFMA mech MLP (X fragment straight from L2,
//                          no smX; fallback prediction reads f32 exact)
//                 bid==0 additionally writes adj + scores diagonal.
//   bid 256..495: pair MLP block p = bid-256, writes its scores cell.
//
// d_out (f32): [0,256) adj | [256,131328) predictions | [131328,131584) scores
// d_ws: UNUSED (no flags, no partials).

typedef __attribute__((ext_vector_type(8))) short bf16x8;
typedef __attribute__((ext_vector_type(4))) short bf16x4;
typedef __attribute__((ext_vector_type(4))) float f32x4;

#define DEV __device__ __forceinline__
DEV short f2bf(float f){ __hip_bfloat16 h = __float2bfloat16(f); short s; __builtin_memcpy(&s,&h,2); return s; }
DEV float bf2f(short s){ __hip_bfloat16 h; __builtin_memcpy(&h,&s,2); return __bfloat162float(h); }

// ---- LDS union: graph phase / mech phase / pair block ----
// avT stride 532: multiple of 4 (16B-aligned float4 rows), 532 % 32 == 20
// -> cov reads conflict-free (i broadcast; 20*j mod 32 is 2-way = free).
struct GraphSm {
    float avT[16 * 532];   // av transposed: avT[v][s], 34048 B
    float part[512];
    float cov[256];
    float corr[256];
    float h1[256];
    float h2[128];
    float adj[256];
    float m[16];
    float stdv[16];
};                          // 40832 B
struct MechSm {
    short W2T[64 * 136];    // Wm2^T bf16, padded row 136
    short H1[4][16 * 136];  // per-wave h1 staging
    float W1[16 * 128];     // layer-1 weights, mask+self folded
    float B1[128];
    float B2[64];
    float W3[64];
};                          // 44032 B
struct PairSm {
    float w0[32], w1[32], bb[32], w2[32];
    float red[256];
    float b2s;
};
union SmU { GraphSm g; MechSm m; PairSm p; };

__global__ void __launch_bounds__(256, 2) k_fused(
    const float* __restrict__ data,
    const float* __restrict__ Ws1, const float* __restrict__ bs1,
    const float* __restrict__ Ws2, const float* __restrict__ bs2,
    const float* __restrict__ Ws3, const float* __restrict__ bs3,
    const float* __restrict__ Wm1, const float* __restrict__ bm1,
    const float* __restrict__ Wm2, const float* __restrict__ bm2,
    const float* __restrict__ Wm3, const float* __restrict__ bm3,
    const float* __restrict__ Wt1, const float* __restrict__ bt1,
    const float* __restrict__ Wt2, const float* __restrict__ bt2,
    float* __restrict__ out)
{
    __shared__ __align__(16) SmU sm;
    __shared__ float pm_s[16];   // outside the union: survives phase flip
    __shared__ float hp_s;
    int tid = threadIdx.x, bid = blockIdx.x;

    if (bid >= 256) {
        // ================= pair MLP block (p = bid-256) =================
        int p = bid - 256;
        int i = p / 15, jr = p % 15;
        int j = jr + (jr >= i ? 1 : 0);
        if (tid < 32) {
            sm.p.w0[tid] = Wt1[p*64 + tid];
            sm.p.w1[tid] = Wt1[p*64 + 32 + tid];
            sm.p.bb[tid] = bt1[p*32 + tid];
            sm.p.w2[tid] = Wt2[p*32 + tid];
        }
        if (tid == 0) sm.p.b2s = bt2[p];
        __syncthreads();
        float b2sv = sm.p.b2s;
        float acc = 0.f;
        for (int it = 0; it < 32; ++it) {
            int s = it*256 + tid;
            float xa = data[s*16 + i];   // one 64B line; xb hits L1
            float xb = data[s*16 + j];
            float z = b2sv;
            #pragma unroll
            for (int h = 0; h < 32; ++h) {
                float t1 = fmaf(xa, sm.p.w0[h], fmaf(xb, sm.p.w1[h], sm.p.bb[h]));
                z = fmaf(fmaxf(t1, 0.f), sm.p.w2[h], z);
            }
            acc += 1.f / (1.f + expf(-z));
        }
        sm.p.red[tid] = acc;
        __syncthreads();
        for (int off = 128; off > 0; off >>= 1) {
            if (tid < off) sm.p.red[tid] += sm.p.red[tid + off];
            __syncthreads();
        }
        if (tid == 0) out[256 + 131072 + i*16 + j] = sm.p.red[0] * (1.f/8192.f);
        return;
    }

    // ==================== mech block (v, chunk) =========================
    int v = bid >> 4, chunk = bid & 15;
    int gs0 = chunk * 512;                 // 512 samples per block

    // ---------- phase A: redundant graph chain (all f32, L2-resident) ----
    {   // A1: av[v][s] = mean over 16 batches; fully coalesced float4 loads
        int vb = (tid & 3) * 4, sg = tid >> 2;     // sg in 0..63
        for (int k = 0; k < 8; ++k) {
            int s = sg + k*64;
            float ax=0.f, ay=0.f, az=0.f, aw=0.f;
            #pragma unroll
            for (int b = 0; b < 16; ++b) {
                float4 d4 = *(const float4*)&data[b*8192 + s*16 + vb];
                ax += d4.x; ay += d4.y; az += d4.z; aw += d4.w;
            }
            sm.g.avT[(vb+0)*532 + s] = ax * 0.0625f;
            sm.g.avT[(vb+1)*532 + s] = ay * 0.0625f;
            sm.g.avT[(vb+2)*532 + s] = az * 0.0625f;
            sm.g.avT[(vb+3)*532 + s] = aw * 0.0625f;
        }
    }
    __syncthreads();
    // A2: per-variable mean over SEQ
    if (tid < 128) {
        int vv = tid >> 3, sgm = tid & 7;
        const float* rp = &sm.g.avT[vv*532 + sgm*64];
        float a0=0.f, a1=0.f, a2=0.f, a3=0.f;
        for (int s = 0; s < 64; s += 4) {
            float4 fa = *(const float4*)&rp[s];
            a0 += fa.x; a1 += fa.y; a2 += fa.z; a3 += fa.w;
        }
        sm.g.part[tid] = (a0+a1)+(a2+a3);
    }
    __syncthreads();
    if (tid < 16) {
        float ms = 0.f;
        #pragma unroll
        for (int q = 0; q < 8; ++q) ms += sm.g.part[tid*8 + q];
        sm.g.m[tid] = ms * (1.f/512.f);
    }
    __syncthreads();
    {   // A3: cov, symmetry-split halves of the s-range (halves LDS reads)
        int ci = tid >> 4, cj = tid & 15;
        int slo = (ci <= cj) ? 0   : 256;
        int shi = (ci <  cj) ? 256 : 512;   // diag threads do full range
        const float* pi_ = &sm.g.avT[ci*532];
        const float* pj_ = &sm.g.avT[cj*532];
        float a0=0.f, a1=0.f, a2=0.f, a3=0.f;
        for (int s = slo; s < shi; s += 4) {
            float4 fa = *(const float4*)&pi_[s];
            float4 fb = *(const float4*)&pj_[s];
            a0 = fmaf(fa.x, fb.x, a0); a1 = fmaf(fa.y, fb.y, a1);
            a2 = fmaf(fa.z, fb.z, a2); a3 = fmaf(fa.w, fb.w, a3);
        }
        sm.g.part[tid] = (a0+a1)+(a2+a3);
    }
    __syncthreads();
    {
        int ci = tid >> 4, cj = tid & 15;
        float raw = (ci == cj) ? sm.g.part[tid]
                               : sm.g.part[ci*16+cj] + sm.g.part[cj*16+ci];
        sm.g.cov[tid] = raw - 512.f * sm.g.m[ci] * sm.g.m[cj];
    }
    __syncthreads();
    if (tid < 16) sm.g.stdv[tid] = sqrtf(fmaxf(sm.g.cov[tid*17], 0.f));
    __syncthreads();
    {
        int ci = tid >> 4, cj = tid & 15;
        float den = sm.g.stdv[ci] * sm.g.stdv[cj];
        sm.g.corr[tid] = (den > 0.f && ci != cj) ? fabsf(sm.g.cov[tid]/den) : 0.f;
    }
    __syncthreads();
    {   // layer1: 256 outputs, K=256 (coalesced Ws1 column reads)
        float a0=0.f, a1=0.f, a2=0.f, a3=0.f;
        const float* cp = sm.g.corr;
        #pragma unroll 4
        for (int k = 0; k < 256; k += 4) {
            a0 = fmaf(cp[k  ], Ws1[(k  )*256 + tid], a0);
            a1 = fmaf(cp[k+1], Ws1[(k+1)*256 + tid], a1);
            a2 = fmaf(cp[k+2], Ws1[(k+2)*256 + tid], a2);
            a3 = fmaf(cp[k+3], Ws1[(k+3)*256 + tid], a3);
        }
        sm.g.h1[tid] = fmaxf((a0+a1)+(a2+a3) + bs1[tid], 0.f);
    }
    __syncthreads();
    {   // layer2: 128 outputs, K=256 split in 2
        int t = tid & 127, half = tid >> 7;
        const float* h1p = sm.g.h1 + half*128;
        const float* W2p = Ws2 + half*128*128;
        float a0=0.f, a1=0.f, a2=0.f, a3=0.f;
        #pragma unroll 4
        for (int k = 0; k < 128; k += 4) {
            a0 = fmaf(h1p[k  ], W2p[(k  )*128 + t], a0);
            a1 = fmaf(h1p[k+1], W2p[(k+1)*128 + t], a1);
            a2 = fmaf(h1p[k+2], W2p[(k+2)*128 + t], a2);
            a3 = fmaf(h1p[k+3], W2p[(k+3)*128 + t], a3);
        }
        sm.g.part[tid] = (a0+a1)+(a2+a3);
    }
    __syncthreads();
    if (tid < 128)
        sm.g.h2[tid] = fmaxf(sm.g.part[tid] + sm.g.part[128+tid] + bs2[tid], 0.f);
    __syncthreads();
    {   // layer3: 256 outputs, K=128 -> adj
        float a0=0.f, a1=0.f, a2=0.f, a3=0.f;
        const float* h2p = sm.g.h2;
        #pragma unroll 4
        for (int k = 0; k < 128; k += 4) {
            a0 = fmaf(h2p[k  ], Ws3[(k  )*256 + tid], a0);
            a1 = fmaf(h2p[k+1], Ws3[(k+1)*256 + tid], a1);
            a2 = fmaf(h2p[k+2], Ws3[(k+2)*256 + tid], a2);
            a3 = fmaf(h2p[k+3], Ws3[(k+3)*256 + tid], a3);
        }
        float z = (a0+a1)+(a2+a3) + bs3[tid];
        float a = 1.f / (1.f + expf(-z));
        int r = tid >> 4, cc = tid & 15;
        float adjv = (r < cc) ? a : 0.f;           // triu(adj,1)
        sm.g.adj[tid] = adjv;
        if (bid == 0) out[tid] = adjv;             // one block owns adj write
    }
    __syncthreads();
    // pm/hp for OUR v (bit-identical across blocks: same ops, same order)
    if (tid < 15) {
        int jj = tid + (tid >= v ? 1 : 0);
        pm_s[tid] = (sm.g.adj[jj*16 + v] > 0.5f) ? 1.f : 0.f;
    }
    if (bid == 0 && tid >= 16 && tid < 32)
        out[256 + 131072 + (tid-16)*17] = 0.f;     // scores diagonal
    __syncthreads();
    if (tid == 0) {
        float s = 0.f;
        #pragma unroll
        for (int pr = 0; pr < 15; ++pr) s += pm_s[pr];
        hp_s = (s > 0.f) ? 1.f : 0.f;
    }
    __syncthreads();   // union flips: graph arrays dead from here

    // ---------- phase B: bf16-MFMA mech MLP (512 samples) ---------------
    for (int e = tid; e < 2048; e += 256) {        // Wfull (mask+self folded)
        int k = e >> 7, h = e & 127;
        float val = 0.f;
        if (k != v) {
            int p = k - (k > v ? 1 : 0);
            val = Wm1[v*1920 + p*128 + h] * pm_s[p];
        }
        sm.m.W1[e] = val;
    }
    for (int e = tid; e < 8192; e += 256) {        // Wm2^T -> bf16
        int h = e >> 6, jj2 = e & 63;
        sm.m.W2T[jj2*136 + h] = f2bf(Wm2[v*8192 + e]);
    }
    if (tid < 128) sm.m.B1[tid] = bm1[v*128 + tid];
    else if (tid < 192) sm.m.B2[tid - 128] = bm2[v*64 + tid - 128];
    else sm.m.W3[tid - 192] = Wm3[v*64 + tid - 192];
    __syncthreads();

    int lane = tid & 63, wid = tid >> 6;
    int c = lane & 15, q = lane >> 4;
    float hp = hp_s;
    float bm3v = bm3[v];

    bf16x8 a1f[8];
    #pragma unroll
    for (int ht = 0; ht < 8; ++ht) {
        #pragma unroll
        for (int jj = 0; jj < 8; ++jj) {
            int k = q*8 + jj;
            float w = (k < 16) ? sm.m.W1[k*128 + ht*16 + c] : 0.f;
            a1f[ht][jj] = f2bf(w);
        }
    }
    bf16x8 b2r[16];
    #pragma unroll
    for (int jt = 0; jt < 4; ++jt)
        #pragma unroll
        for (int ks = 0; ks < 4; ++ks)
            b2r[jt*4 + ks] = *(const bf16x8*)&sm.m.W2T[(jt*16 + c)*136 + ks*32 + q*8];
    float w3c[4], b2c[4];
    #pragma unroll
    for (int jt = 0; jt < 4; ++jt) { w3c[jt] = sm.m.W3[jt*16 + c]; b2c[jt] = sm.m.B2[jt*16 + c]; }

    short* h1buf = sm.m.H1[wid];

    for (int stl = 0; stl < 8; ++stl) {
        int st = wid*8 + stl;                       // 0..31 (512 samples)
        bf16x8 xb;
        #pragma unroll
        for (int i2 = 0; i2 < 8; ++i2) xb[i2] = 0;
        if (q < 2) {                                // X fragment from L2
            const float* xp = &data[(gs0 + st*16 + c)*16 + q*8];
            float4 u0 = *(const float4*)xp;
            float4 u1 = *(const float4*)(xp + 4);
            xb[0] = f2bf(u0.x); xb[1] = f2bf(u0.y);
            xb[2] = f2bf(u0.z); xb[3] = f2bf(u0.w);
            xb[4] = f2bf(u1.x); xb[5] = f2bf(u1.y);
            xb[6] = f2bf(u1.z); xb[7] = f2bf(u1.w);
        }
        f32x4 c1[8];
        #pragma unroll
        for (int ht = 0; ht < 8; ++ht) c1[ht] = *(const f32x4*)&sm.m.B1[ht*16 + q*4];
        #pragma unroll
        for (int ht = 0; ht < 8; ++ht)
            c1[ht] = __builtin_amdgcn_mfma_f32_16x16x32_bf16(a1f[ht], xb, c1[ht], 0, 0, 0);
        #pragma unroll
        for (int ht = 0; ht < 8; ++ht) {
            bf16x4 pk;
            #pragma unroll
            for (int r = 0; r < 4; ++r) pk[r] = f2bf(fmaxf(c1[ht][r], 0.f));
            *(bf16x4*)&h1buf[c*136 + ht*16 + q*4] = pk;
        }
        f32x4 c2[4];
        #pragma unroll
        for (int jt = 0; jt < 4; ++jt) {
            float bi = b2c[jt];
            c2[jt] = (f32x4){bi, bi, bi, bi};
        }
        #pragma unroll
        for (int ks = 0; ks < 4; ++ks) {
            bf16x8 a2 = *(const bf16x8*)&h1buf[c*136 + ks*32 + q*8];
            #pragma unroll
            for (int jt = 0; jt < 4; ++jt)
                c2[jt] = __builtin_amdgcn_mfma_f32_16x16x32_bf16(a2, b2r[jt*4 + ks], c2[jt], 0, 0, 0);
        }
        float part[4];
        #pragma unroll
        for (int r = 0; r < 4; ++r) part[r] = 0.f;
        #pragma unroll
        for (int jt = 0; jt < 4; ++jt)
            #pragma unroll
            for (int r = 0; r < 4; ++r)
                part[r] = fmaf(fmaxf(c2[jt][r], 0.f), w3c[jt], part[r]);
        #pragma unroll
        for (int off = 1; off < 16; off <<= 1)
            #pragma unroll
            for (int r = 0; r < 4; ++r)
                part[r] += __shfl_xor(part[r], off, 16);
        if (c == 0) {
            #pragma unroll
            for (int r = 0; r < 4; ++r) {
                int s_loc = st*16 + q*4 + r;
                float mech = part[r] + bm3v;
                float xv = data[(gs0 + s_loc)*16 + v];   // f32 exact fallback
                out[256 + (gs0 + s_loc)*16 + v] = (hp != 0.f) ? mech : xv;
            }
        }
    }
}

// ---------------------------------------------------------------- launch
extern "C" void kernel_launch(void* const* d_in, const int* in_sizes, int n_in,
                              void* d_out, int out_size, void* d_ws, size_t ws_size,
                              hipStream_t stream)
{
    const float* data = (const float*)d_in[0];
    const float* Ws1  = (const float*)d_in[1];
    const float* bs1  = (const float*)d_in[2];
    const float* Ws2  = (const float*)d_in[3];
    const float* bs2  = (const float*)d_in[4];
    const float* Ws3  = (const float*)d_in[5];
    const float* bs3  = (const float*)d_in[6];
    const float* Wm1  = (const float*)d_in[7];
    const float* bm1  = (const float*)d_in[8];
    const float* Wm2  = (const float*)d_in[9];
    const float* bm2  = (const float*)d_in[10];
    const float* Wm3  = (const float*)d_in[11];
    const float* bm3  = (const float*)d_in[12];
    const float* Wt1  = (const float*)d_in[13];
    const float* bt1  = (const float*)d_in[14];
    const float* Wt2  = (const float*)d_in[15];
    const float* bt2  = (const float*)d_in[16];
    float* out = (float*)d_out;
    (void)d_ws; (void)ws_size;

    hipLaunchKernelGGL(k_fused, dim3(496), dim3(256), 0, stream,
                       data, Ws1, bs1, Ws2, bs2, Ws3, bs3,
                       Wm1, bm1, Wm2, bm2, Wm3, bm3,
                       Wt1, bt1, Wt2, bt2, out);
}

// Round 2
// 125.469 us; speedup vs baseline: 1.0394x; 1.0394x over previous
//
#include <hip/hip_runtime.h>
#include <hip/hip_bf16.h>

// CausalGraphDiscovery on MI355X. f32 buffers holding bf16-rounded values.
// Round 8: single dispatch, zero inter-block deps (keep round-7 structure),
// but cut graph-chain redundancy 4x: 64 mech blocks (16v x 4 chunks of 2048
// samples) at 512 threads, instead of 256 blocks at 256 threads.
//   Round-7 counters: k_fused 52us, HBM 1.8%, Mfma 2%, VALU 30%, occ 15%
//   -> latency/L2-contention bound on 256x-redundant graph recompute
//   (256 blocks x ~1MB L2 reads + ~6k VALU/thread of graph chain).
//   This round: redundancy 256->64 (L2 graph traffic 256->64MB, aggregate
//   graph VALU /4), 8-wave blocks hide per-pass L2 latency, pair blocks
//   512-thread with ILP-split z-chain + fast sigmoid.
//
// Grid: 304 blocks x 512 threads.
//   bid  0..63 : mech block (v = bid>>2, chunk = bid&3 -> 2048 samples)
//                phase A: graph chain (identical f32 op order in every block
//                         -> bit-identical adj -> consistent pm)
//                phase B: bf16-MFMA mech MLP; bid==0 writes adj + scores diag.
//   bid 64..303: pair MLP block p = bid-64, writes its scores cell.
//
// d_out (f32): [0,256) adj | [256,131328) predictions | [131328,131584) scores
// d_ws: UNUSED.

typedef __attribute__((ext_vector_type(8))) short bf16x8;
typedef __attribute__((ext_vector_type(4))) short bf16x4;
typedef __attribute__((ext_vector_type(4))) float f32x4;

#define DEV __device__ __forceinline__
DEV short f2bf(float f){ __hip_bfloat16 h = __float2bfloat16(f); short s; __builtin_memcpy(&s,&h,2); return s; }

// ---- LDS union ----
// avT stride 532: multiple of 4 (16B-aligned float4 rows); 532 % 32 == 20
// -> cov reads ~2-way conflicts (free on CDNA4).
struct GraphSm {
    float avT[16 * 532];   // av transposed: avT[v][s], 34048 B
    float part[512];
    float cov[256];
    float corr[256];
    float h1[256];
    float h2[128];
    float adj[256];
    float m[16];
    float stdv[16];
};                          // 40832 B
struct MechSm {
    short W2T[64 * 136];    // Wm2^T bf16, padded row 136       17408 B
    short H1[8][16 * 136];  // per-wave h1 staging              34816 B
    float W1[16 * 128];     // layer-1 weights, mask+self folded 8192 B
    float B1[128];
    float B2[64];
    float W3[64];
};                          // 61440 B
struct PairSm {
    float w0[32], w1[32], bb[32], w2[32];
    float red[512];
    float b2s;
};
union SmU { GraphSm g; MechSm m; PairSm p; };

__global__ void __launch_bounds__(512, 2) k_fused(
    const float* __restrict__ data,
    const float* __restrict__ Ws1, const float* __restrict__ bs1,
    const float* __restrict__ Ws2, const float* __restrict__ bs2,
    const float* __restrict__ Ws3, const float* __restrict__ bs3,
    const float* __restrict__ Wm1, const float* __restrict__ bm1,
    const float* __restrict__ Wm2, const float* __restrict__ bm2,
    const float* __restrict__ Wm3, const float* __restrict__ bm3,
    const float* __restrict__ Wt1, const float* __restrict__ bt1,
    const float* __restrict__ Wt2, const float* __restrict__ bt2,
    float* __restrict__ out)
{
    __shared__ __align__(16) SmU sm;
    __shared__ float pm_s[16];   // outside the union: survives phase flip
    __shared__ float hp_s;
    int tid = threadIdx.x, bid = blockIdx.x;

    if (bid >= 64) {
        // ================= pair MLP block (p = bid-64) ==================
        int p = bid - 64;
        int i = p / 15, jr = p % 15;
        int j = jr + (jr >= i ? 1 : 0);
        if (tid < 32) {
            sm.p.w0[tid] = Wt1[p*64 + tid];
            sm.p.w1[tid] = Wt1[p*64 + 32 + tid];
            sm.p.bb[tid] = bt1[p*32 + tid];
            sm.p.w2[tid] = Wt2[p*32 + tid];
        }
        if (tid == 0) sm.p.b2s = bt2[p];
        __syncthreads();
        float b2sv = sm.p.b2s;
        float acc = 0.f;
        for (int it = 0; it < 16; ++it) {
            int s = it*512 + tid;
            float xa = data[s*16 + i];   // one 64B line; xb hits L1
            float xb = data[s*16 + j];
            float za = 0.f, zb = 0.f;    // 2-way ILP split of serial chain
            #pragma unroll
            for (int h = 0; h < 32; h += 2) {
                float t1 = fmaf(xa, sm.p.w0[h],   fmaf(xb, sm.p.w1[h],   sm.p.bb[h]));
                za = fmaf(fmaxf(t1, 0.f), sm.p.w2[h],   za);
                float t2 = fmaf(xa, sm.p.w0[h+1], fmaf(xb, sm.p.w1[h+1], sm.p.bb[h+1]));
                zb = fmaf(fmaxf(t2, 0.f), sm.p.w2[h+1], zb);
            }
            float z = b2sv + za + zb;
            // fast sigmoid: scores are an 8192-sample mean, tol 1.6e-2
            acc += __builtin_amdgcn_rcpf(1.f + __expf(-z));
        }
        sm.p.red[tid] = acc;
        __syncthreads();
        for (int off = 256; off > 0; off >>= 1) {
            if (tid < off) sm.p.red[tid] += sm.p.red[tid + off];
            __syncthreads();
        }
        if (tid == 0) out[256 + 131072 + i*16 + j] = sm.p.red[0] * (1.f/8192.f);
        return;
    }

    // ==================== mech block (v, chunk) =========================
    int v = bid >> 2, chunk = bid & 3;
    int gs0 = chunk * 2048;                // 2048 samples per block

    // ---------- phase A: redundant graph chain (all f32, L2-resident) ----
    {   // A1: av[v][s] = mean over 16 batches; coalesced float4 loads
        int vb = (tid & 3) * 4, sg = tid >> 2;     // sg in 0..127
        for (int k = 0; k < 4; ++k) {
            int s = sg + k*128;
            float ax=0.f, ay=0.f, az=0.f, aw=0.f;
            #pragma unroll
            for (int b = 0; b < 16; ++b) {
                float4 d4 = *(const float4*)&data[b*8192 + s*16 + vb];
                ax += d4.x; ay += d4.y; az += d4.z; aw += d4.w;
            }
            sm.g.avT[(vb+0)*532 + s] = ax * 0.0625f;
            sm.g.avT[(vb+1)*532 + s] = ay * 0.0625f;
            sm.g.avT[(vb+2)*532 + s] = az * 0.0625f;
            sm.g.avT[(vb+3)*532 + s] = aw * 0.0625f;
        }
    }
    __syncthreads();
    // A2: per-variable mean over SEQ
    if (tid < 128) {
        int vv = tid >> 3, sgm = tid & 7;
        const float* rp = &sm.g.avT[vv*532 + sgm*64];
        float a0=0.f, a1=0.f, a2=0.f, a3=0.f;
        for (int s = 0; s < 64; s += 4) {
            float4 fa = *(const float4*)&rp[s];
            a0 += fa.x; a1 += fa.y; a2 += fa.z; a3 += fa.w;
        }
        sm.g.part[tid] = (a0+a1)+(a2+a3);
    }
    __syncthreads();
    if (tid < 16) {
        float ms = 0.f;
        #pragma unroll
        for (int q = 0; q < 8; ++q) ms += sm.g.part[tid*8 + q];
        sm.g.m[tid] = ms * (1.f/512.f);
    }
    __syncthreads();
    {   // A3: cov partials, s-range split in 2 across thread halves
        int t = tid & 255, hh = tid >> 8;
        int ci = t >> 4, cj = t & 15;
        const float* pi_ = &sm.g.avT[ci*532 + hh*256];
        const float* pj_ = &sm.g.avT[cj*532 + hh*256];
        float a0=0.f, a1=0.f, a2=0.f, a3=0.f;
        for (int s = 0; s < 256; s += 4) {
            float4 fa = *(const float4*)&pi_[s];
            float4 fb = *(const float4*)&pj_[s];
            a0 = fmaf(fa.x, fb.x, a0); a1 = fmaf(fa.y, fb.y, a1);
            a2 = fmaf(fa.z, fb.z, a2); a3 = fmaf(fa.w, fb.w, a3);
        }
        sm.g.part[tid] = (a0+a1)+(a2+a3);
    }
    __syncthreads();
    if (tid < 256) {
        int ci = tid >> 4, cj = tid & 15;
        sm.g.cov[tid] = sm.g.part[tid] + sm.g.part[256 + tid]
                      - 512.f * sm.g.m[ci] * sm.g.m[cj];
    }
    __syncthreads();
    if (tid < 16) sm.g.stdv[tid] = sqrtf(fmaxf(sm.g.cov[tid*17], 0.f));
    __syncthreads();
    if (tid < 256) {
        int ci = tid >> 4, cj = tid & 15;
        float den = sm.g.stdv[ci] * sm.g.stdv[cj];
        sm.g.corr[tid] = (den > 0.f && ci != cj) ? fabsf(sm.g.cov[tid]/den) : 0.f;
    }
    __syncthreads();
    {   // layer1: 256 outputs, K=256 split in 2 halves across 512 threads
        int t = tid & 255, half = tid >> 8;
        const float* W1p = Ws1 + half*128*256;
        const float* cp  = sm.g.corr + half*128;
        float a0=0.f, a1=0.f, a2=0.f, a3=0.f;
        #pragma unroll 8
        for (int i = 0; i < 128; i += 4) {
            a0 = fmaf(cp[i  ], W1p[(i  )*256 + t], a0);
            a1 = fmaf(cp[i+1], W1p[(i+1)*256 + t], a1);
            a2 = fmaf(cp[i+2], W1p[(i+2)*256 + t], a2);
            a3 = fmaf(cp[i+3], W1p[(i+3)*256 + t], a3);
        }
        sm.g.part[half*256 + t] = (a0+a1)+(a2+a3);
    }
    __syncthreads();
    if (tid < 256) sm.g.h1[tid] = fmaxf(sm.g.part[tid] + sm.g.part[256+tid] + bs1[tid], 0.f);
    __syncthreads();
    {   // layer2: 128 outputs, K=256 split in 4
        int t = tid & 127, qq = tid >> 7;
        const float* W2p = Ws2 + qq*64*128;
        const float* h1p = sm.g.h1 + qq*64;
        float a0=0.f, a1=0.f, a2=0.f, a3=0.f;
        #pragma unroll 4
        for (int i = 0; i < 64; i += 4) {
            a0 = fmaf(h1p[i  ], W2p[(i  )*128 + t], a0);
            a1 = fmaf(h1p[i+1], W2p[(i+1)*128 + t], a1);
            a2 = fmaf(h1p[i+2], W2p[(i+2)*128 + t], a2);
            a3 = fmaf(h1p[i+3], W2p[(i+3)*128 + t], a3);
        }
        sm.g.part[qq*128 + t] = (a0+a1)+(a2+a3);
    }
    __syncthreads();
    if (tid < 128)
        sm.g.h2[tid] = fmaxf(sm.g.part[tid] + sm.g.part[128+tid] + sm.g.part[256+tid]
                             + sm.g.part[384+tid] + bs2[tid], 0.f);
    __syncthreads();
    {   // layer3: 256 outputs, K=128 split in 2
        int t = tid & 255, half = tid >> 8;
        const float* W3p = Ws3 + half*64*256;
        const float* h2p = sm.g.h2 + half*64;
        float a0=0.f, a1=0.f, a2=0.f, a3=0.f;
        #pragma unroll 4
        for (int i = 0; i < 64; i += 4) {
            a0 = fmaf(h2p[i  ], W3p[(i  )*256 + t], a0);
            a1 = fmaf(h2p[i+1], W3p[(i+1)*256 + t], a1);
            a2 = fmaf(h2p[i+2], W3p[(i+2)*256 + t], a2);
            a3 = fmaf(h2p[i+3], W3p[(i+3)*256 + t], a3);
        }
        sm.g.part[half*256 + t] = (a0+a1)+(a2+a3);
    }
    __syncthreads();
    if (tid < 256) {
        float z = sm.g.part[tid] + sm.g.part[256 + tid] + bs3[tid];
        float a = 1.f / (1.f + expf(-z));          // precise: feeds 0.5 threshold
        int r = tid >> 4, cc = tid & 15;
        float adjv = (r < cc) ? a : 0.f;           // triu(adj,1)
        sm.g.adj[tid] = adjv;
        if (bid == 0) out[tid] = adjv;             // one block owns adj write
    }
    __syncthreads();
    // pm/hp for OUR v (bit-identical across blocks: same ops, same data)
    if (tid < 15) {
        int jj = tid + (tid >= v ? 1 : 0);
        pm_s[tid] = (sm.g.adj[jj*16 + v] > 0.5f) ? 1.f : 0.f;
    }
    if (bid == 0 && tid >= 16 && tid < 32)
        out[256 + 131072 + (tid-16)*17] = 0.f;     // scores diagonal
    __syncthreads();
    if (tid == 0) {
        float s = 0.f;
        #pragma unroll
        for (int pr = 0; pr < 15; ++pr) s += pm_s[pr];
        hp_s = (s > 0.f) ? 1.f : 0.f;
    }
    __syncthreads();   // union flips: graph arrays dead from here

    // ---------- phase B: bf16-MFMA mech MLP (2048 samples) ---------------
    for (int e = tid; e < 2048; e += 512) {        // Wfull (mask+self folded)
        int k = e >> 7, h = e & 127;
        float val = 0.f;
        if (k != v) {
            int p = k - (k > v ? 1 : 0);
            val = Wm1[v*1920 + p*128 + h] * pm_s[p];
        }
        sm.m.W1[e] = val;
    }
    for (int e = tid; e < 8192; e += 512) {        // Wm2^T -> bf16
        int h = e >> 6, jj2 = e & 63;
        sm.m.W2T[jj2*136 + h] = f2bf(Wm2[v*8192 + e]);
    }
    if (tid < 128) sm.m.B1[tid] = bm1[v*128 + tid];
    else if (tid < 192) sm.m.B2[tid - 128] = bm2[v*64 + tid - 128];
    else if (tid < 256) sm.m.W3[tid - 192] = Wm3[v*64 + tid - 192];
    __syncthreads();

    int lane = tid & 63, wid = tid >> 6;           // wid 0..7
    int c = lane & 15, q = lane >> 4;
    float hp = hp_s;
    float bm3v = bm3[v];

    bf16x8 a1f[8];
    #pragma unroll
    for (int ht = 0; ht < 8; ++ht) {
        #pragma unroll
        for (int jj = 0; jj < 8; ++jj) {
            int k = q*8 + jj;
            float w = (k < 16) ? sm.m.W1[k*128 + ht*16 + c] : 0.f;
            a1f[ht][jj] = f2bf(w);
        }
    }
    bf16x8 b2r[16];
    #pragma unroll
    for (int jt = 0; jt < 4; ++jt)
        #pragma unroll
        for (int ks = 0; ks < 4; ++ks)
            b2r[jt*4 + ks] = *(const bf16x8*)&sm.m.W2T[(jt*16 + c)*136 + ks*32 + q*8];
    float w3c[4], b2c[4];
    #pragma unroll
    for (int jt = 0; jt < 4; ++jt) { w3c[jt] = sm.m.W3[jt*16 + c]; b2c[jt] = sm.m.B2[jt*16 + c]; }

    short* h1buf = sm.m.H1[wid];

    for (int stl = 0; stl < 16; ++stl) {
        int st = wid*16 + stl;                      // 0..127 (2048 samples)
        bf16x8 xb;
        #pragma unroll
        for (int i2 = 0; i2 < 8; ++i2) xb[i2] = 0;
        if (q < 2) {                                // X fragment from L2
            const float* xp = &data[(gs0 + st*16 + c)*16 + q*8];
            float4 u0 = *(const float4*)xp;
            float4 u1 = *(const float4*)(xp + 4);
            xb[0] = f2bf(u0.x); xb[1] = f2bf(u0.y);
            xb[2] = f2bf(u0.z); xb[3] = f2bf(u0.w);
            xb[4] = f2bf(u1.x); xb[5] = f2bf(u1.y);
            xb[6] = f2bf(u1.z); xb[7] = f2bf(u1.w);
        }
        f32x4 c1[8];
        #pragma unroll
        for (int ht = 0; ht < 8; ++ht) c1[ht] = *(const f32x4*)&sm.m.B1[ht*16 + q*4];
        #pragma unroll
        for (int ht = 0; ht < 8; ++ht)
            c1[ht] = __builtin_amdgcn_mfma_f32_16x16x32_bf16(a1f[ht], xb, c1[ht], 0, 0, 0);
        #pragma unroll
        for (int ht = 0; ht < 8; ++ht) {
            bf16x4 pk;
            #pragma unroll
            for (int r = 0; r < 4; ++r) pk[r] = f2bf(fmaxf(c1[ht][r], 0.f));
            *(bf16x4*)&h1buf[c*136 + ht*16 + q*4] = pk;
        }
        f32x4 c2[4];
        #pragma unroll
        for (int jt = 0; jt < 4; ++jt) {
            float bi = b2c[jt];
            c2[jt] = (f32x4){bi, bi, bi, bi};
        }
        #pragma unroll
        for (int ks = 0; ks < 4; ++ks) {
            bf16x8 a2 = *(const bf16x8*)&h1buf[c*136 + ks*32 + q*8];
            #pragma unroll
            for (int jt = 0; jt < 4; ++jt)
                c2[jt] = __builtin_amdgcn_mfma_f32_16x16x32_bf16(a2, b2r[jt*4 + ks], c2[jt], 0, 0, 0);
        }
        float part[4];
        #pragma unroll
        for (int r = 0; r < 4; ++r) part[r] = 0.f;
        #pragma unroll
        for (int jt = 0; jt < 4; ++jt)
            #pragma unroll
            for (int r = 0; r < 4; ++r)
                part[r] = fmaf(fmaxf(c2[jt][r], 0.f), w3c[jt], part[r]);
        #pragma unroll
        for (int off = 1; off < 16; off <<= 1)
            #pragma unroll
            for (int r = 0; r < 4; ++r)
                part[r] += __shfl_xor(part[r], off, 16);
        if (c == 0) {
            #pragma unroll
            for (int r = 0; r < 4; ++r) {
                int s_loc = st*16 + q*4 + r;
                float mech = part[r] + bm3v;
                float xv = data[(gs0 + s_loc)*16 + v];   // f32 exact fallback
                out[256 + (gs0 + s_loc)*16 + v] = (hp != 0.f) ? mech : xv;
            }
        }
    }
}

// ---------------------------------------------------------------- launch
extern "C" void kernel_launch(void* const* d_in, const int* in_sizes, int n_in,
                              void* d_out, int out_size, void* d_ws, size_t ws_size,
                              hipStream_t stream)
{
    const float* data = (const float*)d_in[0];
    const float* Ws1  = (const float*)d_in[1];
    const float* bs1  = (const float*)d_in[2];
    const float* Ws2  = (const float*)d_in[3];
    const float* bs2  = (const float*)d_in[4];
    const float* Ws3  = (const float*)d_in[5];
    const float* bs3  = (const float*)d_in[6];
    const float* Wm1  = (const float*)d_in[7];
    const float* bm1  = (const float*)d_in[8];
    const float* Wm2  = (const float*)d_in[9];
    const float* bm2  = (const float*)d_in[10];
    const float* Wm3  = (const float*)d_in[11];
    const float* bm3  = (const float*)d_in[12];
    const float* Wt1  = (const float*)d_in[13];
    const float* bt1  = (const float*)d_in[14];
    const float* Wt2  = (const float*)d_in[15];
    const float* bt2  = (const float*)d_in[16];
    float* out = (float*)d_out;
    (void)d_ws; (void)ws_size; (void)in_sizes; (void)n_in; (void)out_size;

    hipLaunchKernelGGL(k_fused, dim3(304), dim3(512), 0, stream,
                       data, Ws1, bs1, Ws2, bs2, Ws3, bs3,
                       Wm1, bm1, Wm2, bm2, Wm3, bm3,
                       Wt1, bt1, Wt2, bt2, out);
}